// Round 1
// baseline (200.175 us; speedup 1.0000x reference)
//
#include <hip/hip_runtime.h>
#include <stdint.h>

// Problem: cosine-similarity relations.
//   support: (2,5,1024,128) fp32 -> 10240 rows; query: (2,4,1024,128) -> 8192 rows
//   out: (2,4,5,1024,1024) fp32 = 167.8 MB  -> write-BW floor ~27 us
// R5 -> R6 theory: R5 (174 us) was latency-bound, not BW-bound. 64 KB LDS/block
// capped occupancy at 2 blocks/CU (8 waves), and the stage->barrier->compute
// chain exposed full L2/L3 read latency every tile. But the normalized bf16
// working set (qn+sn = 4.7 MB) is L2/L3-resident -- LDS staging of cache-fit
// data is pure overhead (guide Common-mistake #7). R6 removes LDS and barriers
// entirely: MFMA fragments are loaded straight from global (per instruction:
// 16 rows x one 64B segment -- quads 0..3 cover 4 consecutive 16B k-chunks of
// each row), L1/L2 serve the reuse. Occupancy becomes VGPR-limited (~12
// waves/CU via __launch_bounds__(256,3)) and the compiler can pipeline loads
// across the unrolled K loop with no sync points. Epilogue uses nontemporal
// stores so the 167.8 MB write-once stream doesn't evict qn/sn from L2.

#define S_ROWS 10240
#define Q_ROWS 8192

typedef __attribute__((ext_vector_type(8))) short short8;   // 8 bf16 (4 VGPRs)
typedef __attribute__((ext_vector_type(4))) float floatx4;  // 16x16 MFMA acc

__device__ static inline unsigned short f32_to_bf16_rne(float f) {
    union { float f; uint32_t u; } c; c.f = f;
    uint32_t u = c.u;
    uint32_t r = u + 0x7FFFu + ((u >> 16) & 1u);   // round-to-nearest-even
    return (unsigned short)(r >> 16);
}

// ---------------- Kernel 1: L2-normalize rows of 128, cast to bf16 ----------
__global__ __launch_bounds__(256) void norm_cast_kernel(
    const float* __restrict__ support, const float* __restrict__ query,
    unsigned short* __restrict__ sn, unsigned short* __restrict__ qn)
{
    int wave = blockIdx.x * 4 + (threadIdx.x >> 6);
    int lane = threadIdx.x & 63;

    const float* src;
    unsigned short* dst;
    if (wave < S_ROWS) {
        src = support + (size_t)wave * 128;
        dst = sn + (size_t)wave * 128;
    } else {
        int r = wave - S_ROWS;
        src = query + (size_t)r * 128;
        dst = qn + (size_t)r * 128;
    }

    float2 v = ((const float2*)src)[lane];
    float s = v.x * v.x + v.y * v.y;
    #pragma unroll
    for (int off = 32; off > 0; off >>= 1) s += __shfl_xor(s, off, 64);
    float inv = 1.0f / fmaxf(sqrtf(s), 1e-12f);

    unsigned short lo = f32_to_bf16_rne(v.x * inv);
    unsigned short hi = f32_to_bf16_rne(v.y * inv);
    ((uint32_t*)dst)[lane] = ((uint32_t)hi << 16) | (uint32_t)lo;
}

// ---------------- Kernel 2: batched C = Qn * Sn^T via bf16 MFMA -------------
// 256 threads (4 waves), 128x128 tile, 64x64 per wave. NO LDS, NO barriers:
// fragments read directly from global (qn/sn are 4.7 MB total, cache-resident).
// Fragment data is byte-identical to what the R5 swizzled-LDS path produced:
// a[mi] = Qn_tile[wm+mi*16+ml][ (kb*4+quad)*8 .. +8 ]  (verified vs R5 layout).
__global__ __launch_bounds__(256, 3) void gemm_bt_kernel(
    const unsigned short* __restrict__ qn, const unsigned short* __restrict__ sn,
    float* __restrict__ out)
{
    const int tid  = threadIdx.x;
    const int wave = tid >> 6;
    const int lane = tid & 63;

    const int tn  = blockIdx.x & 7;
    const int tm  = blockIdx.x >> 3;
    const int y   = blockIdx.y;          // 0..39 -> (b,i,j)
    const int b   = y / 20;
    const int rem = y % 20;
    const int i   = rem / 5;
    const int j   = rem % 5;

    const unsigned short* gA = qn + (((size_t)(b * 4 + i) * 1024 + tm * 128) * 128);
    const unsigned short* gB = sn + (((size_t)(b * 5 + j) * 1024 + tn * 128) * 128);

    const int wm   = (wave >> 1) * 64;
    const int wn   = (wave & 1) * 64;
    const int ml   = lane & 15;
    const int quad = lane >> 4;

    floatx4 acc[4][4] = {};

    // K = 128 = 4 kb-steps of 32. Per step, each lane loads its 16B A/B
    // fragments straight from global. Per load instruction the wave touches
    // 16 rows x 64B contiguous (quads 0..3 are 4 consecutive 16B chunks) --
    // 64B-segment coalescing into L1/L2-resident lines. No sync needed.
    #pragma unroll
    for (int kb = 0; kb < 4; ++kb) {
        const int c = kb * 4 + quad;     // 16B k-chunk index
        short8 a[4], bf[4];
        #pragma unroll
        for (int mi = 0; mi < 4; ++mi) {
            const int arow = wm + mi * 16 + ml;
            a[mi] = *(const short8*)&gA[(size_t)arow * 128 + c * 8];
        }
        #pragma unroll
        for (int ni = 0; ni < 4; ++ni) {
            const int brow = wn + ni * 16 + ml;
            bf[ni] = *(const short8*)&gB[(size_t)brow * 128 + c * 8];
        }
        #pragma unroll
        for (int mi = 0; mi < 4; ++mi)
            #pragma unroll
            for (int ni = 0; ni < 4; ++ni)
                acc[mi][ni] = __builtin_amdgcn_mfma_f32_16x16x32_bf16(
                    a[mi], bf[ni], acc[mi][ni], 0, 0, 0);
    }

    // Epilogue: C/D layout col=lane&15, row=quad*4+reg (m89/m91-verified).
    // Nontemporal: output is write-once; keep qn/sn resident in L2.
    float* gC = out + ((size_t)((b * 4 + i) * 5 + j) << 20)
                    + (size_t)(tm * 128) * 1024 + tn * 128;
    #pragma unroll
    for (int mi = 0; mi < 4; ++mi) {
        #pragma unroll
        for (int r = 0; r < 4; ++r) {
            const int row = wm + mi * 16 + quad * 4 + r;
            float* rowp = gC + (size_t)row * 1024 + wn + ml;
            #pragma unroll
            for (int ni = 0; ni < 4; ++ni)
                __builtin_nontemporal_store(acc[mi][ni][r], &rowp[ni * 16]);
        }
    }
}

extern "C" void kernel_launch(void* const* d_in, const int* in_sizes, int n_in,
                              void* d_out, int out_size, void* d_ws, size_t ws_size,
                              hipStream_t stream) {
    const float* support = (const float*)d_in[0];   // (2,5,1024,128)
    const float* query   = (const float*)d_in[1];   // (2,4,1024,128)
    unsigned short* sn = (unsigned short*)d_ws;             // 10240*128 bf16
    unsigned short* qn = sn + (size_t)S_ROWS * 128;         //  8192*128 bf16
    float* out = (float*)d_out;

    norm_cast_kernel<<<dim3((S_ROWS + Q_ROWS) / 4), dim3(256), 0, stream>>>(
        support, query, sn, qn);
    gemm_bt_kernel<<<dim3(64, 40), dim3(256), 0, stream>>>(qn, sn, out);
}

// Round 2
// 187.330 us; speedup vs baseline: 1.0686x; 1.0686x over previous
//
#include <hip/hip_runtime.h>
#include <stdint.h>

// Problem: cosine-similarity relations.
//   support: (2,5,1024,128) fp32 -> 10240 rows; query: (2,4,1024,128) -> 8192 rows
//   out: (2,4,5,1024,1024) fp32 = 167.8 MB  -> write floor ~27 us
// R6 POST-MORTEM: no-LDS direct-global fragments regressed 174->200 us. Each
// fragment load = 16 discontiguous 64B segments -> vmem/TA-issue-bound.
// Reverted to R5's LDS structure (known best, 174 us).
// R7 theory: R5's gap vs the ~30 us floor is L2 eviction by the store stream.
// Each XCD's read set (~2.4 MB: all qn + its tn-slice of sn under the default
// round-robin XCD mapping) fits 4 MiB L2, but ~20 MB/XCD of write-once output
// streams through the same L2 and evicts it -> tile reads fall to L3/HBM
// (~400-900 cy) with only 8 waves/CU to hide. Single change vs R5:
// __builtin_nontemporal_store in the epilogue (nt bit, stores skip L2 LRU).

#define S_ROWS 10240
#define Q_ROWS 8192

typedef __attribute__((ext_vector_type(8))) short short8;   // 8 bf16 (4 VGPRs)
typedef __attribute__((ext_vector_type(4))) float floatx4;  // 16x16 MFMA acc
typedef __attribute__((ext_vector_type(4))) unsigned int uint4x;  // 16 B chunk

__device__ static inline unsigned short f32_to_bf16_rne(float f) {
    union { float f; uint32_t u; } c; c.f = f;
    uint32_t u = c.u;
    uint32_t r = u + 0x7FFFu + ((u >> 16) & 1u);   // round-to-nearest-even
    return (unsigned short)(r >> 16);
}

// ---------------- Kernel 1: L2-normalize rows of 128, cast to bf16 ----------
__global__ __launch_bounds__(256) void norm_cast_kernel(
    const float* __restrict__ support, const float* __restrict__ query,
    unsigned short* __restrict__ sn, unsigned short* __restrict__ qn)
{
    int wave = blockIdx.x * 4 + (threadIdx.x >> 6);
    int lane = threadIdx.x & 63;

    const float* src;
    unsigned short* dst;
    if (wave < S_ROWS) {
        src = support + (size_t)wave * 128;
        dst = sn + (size_t)wave * 128;
    } else {
        int r = wave - S_ROWS;
        src = query + (size_t)r * 128;
        dst = qn + (size_t)r * 128;
    }

    float2 v = ((const float2*)src)[lane];
    float s = v.x * v.x + v.y * v.y;
    #pragma unroll
    for (int off = 32; off > 0; off >>= 1) s += __shfl_xor(s, off, 64);
    float inv = 1.0f / fmaxf(sqrtf(s), 1e-12f);

    unsigned short lo = f32_to_bf16_rne(v.x * inv);
    unsigned short hi = f32_to_bf16_rne(v.y * inv);
    ((uint32_t*)dst)[lane] = ((uint32_t)hi << 16) | (uint32_t)lo;
}

// ---------------- Kernel 2: batched C = Qn * Sn^T via bf16 MFMA -------------
// 256 threads (4 waves), 128x128 tile, 64x64 per wave. A/B tiles staged in
// LDS (64 KB) with XOR-swizzled 16B units; conflict-free ds_read_b128.
__global__ __launch_bounds__(256) void gemm_bt_kernel(
    const unsigned short* __restrict__ qn, const unsigned short* __restrict__ sn,
    float* __restrict__ out)
{
    __shared__ unsigned short As[128 * 128];  // 32 KB, swizzled 16B units
    __shared__ unsigned short Bs[128 * 128];  // 32 KB, swizzled 16B units

    const int tid  = threadIdx.x;
    const int wave = tid >> 6;
    const int lane = tid & 63;

    const int tn = blockIdx.x & 7;
    const int tm = blockIdx.x >> 3;
    const int y   = blockIdx.y;          // 0..39 -> (b,i,j)
    const int b   = y / 20;
    const int rem = y % 20;
    const int i   = rem / 5;
    const int j   = rem % 5;

    const unsigned short* gA = qn + (((size_t)(b * 4 + i) * 1024 + tm * 128) * 128);
    const unsigned short* gB = sn + (((size_t)(b * 5 + j) * 1024 + tn * 128) * 128);

    // Stage 2 x 32 KB. Tile = 2048 16B-units; thread t does units t+256*it.
    // Global loads fully coalesced; ds_write address swizzled.
    uint4x ra[8], rb[8];
    #pragma unroll
    for (int it = 0; it < 8; ++it) {
        ra[it] = ((const uint4x*)gA)[it * 256 + tid];
        rb[it] = ((const uint4x*)gB)[it * 256 + tid];
    }
    #pragma unroll
    for (int it = 0; it < 8; ++it) {
        const int u  = it * 256 + tid;
        const int r  = u >> 4;
        const int cl = u & 15;
        const int su = (r << 4) | (cl ^ (r & 15));   // swizzled LDS unit
        *(uint4x*)&As[su * 8] = ra[it];
        *(uint4x*)&Bs[su * 8] = rb[it];
    }

    const int wm   = (wave >> 1) * 64;
    const int wn   = (wave & 1) * 64;
    const int ml   = lane & 15;
    const int quad = lane >> 4;

    floatx4 acc[4][4] = {};

    __syncthreads();

    #pragma unroll
    for (int kb = 0; kb < 4; ++kb) {
        const int c = kb * 4 + quad;     // 16B-unit column (k-chunk) index
        short8 a[4], bf[4];
        #pragma unroll
        for (int mi = 0; mi < 4; ++mi) {
            const int arow = wm + mi * 16 + ml;          // arow & 15 == ml
            a[mi] = *(const short8*)&As[(((arow << 4) | (c ^ ml))) * 8];
        }
        #pragma unroll
        for (int ni = 0; ni < 4; ++ni) {
            const int brow = wn + ni * 16 + ml;
            bf[ni] = *(const short8*)&Bs[(((brow << 4) | (c ^ ml))) * 8];
        }
        #pragma unroll
        for (int mi = 0; mi < 4; ++mi)
            #pragma unroll
            for (int ni = 0; ni < 4; ++ni)
                acc[mi][ni] = __builtin_amdgcn_mfma_f32_16x16x32_bf16(
                    a[mi], bf[ni], acc[mi][ni], 0, 0, 0);
    }

    // Epilogue: C/D layout col=lane&15, row=quad*4+reg (m89/m91-verified).
    // R7: nontemporal stores -- output is write-once; keep qn/sn in L2.
    float* gC = out + ((size_t)((b * 4 + i) * 5 + j) << 20)
                    + (size_t)(tm * 128) * 1024 + tn * 128;
    #pragma unroll
    for (int mi = 0; mi < 4; ++mi) {
        #pragma unroll
        for (int r = 0; r < 4; ++r) {
            const int row = wm + mi * 16 + quad * 4 + r;
            float* rowp = gC + (size_t)row * 1024 + wn + ml;
            #pragma unroll
            for (int ni = 0; ni < 4; ++ni)
                __builtin_nontemporal_store(acc[mi][ni][r], &rowp[ni * 16]);
        }
    }
}

extern "C" void kernel_launch(void* const* d_in, const int* in_sizes, int n_in,
                              void* d_out, int out_size, void* d_ws, size_t ws_size,
                              hipStream_t stream) {
    const float* support = (const float*)d_in[0];   // (2,5,1024,128)
    const float* query   = (const float*)d_in[1];   // (2,4,1024,128)
    unsigned short* sn = (unsigned short*)d_ws;             // 10240*128 bf16
    unsigned short* qn = sn + (size_t)S_ROWS * 128;         //  8192*128 bf16
    float* out = (float*)d_out;

    norm_cast_kernel<<<dim3((S_ROWS + Q_ROWS) / 4), dim3(256), 0, stream>>>(
        support, query, sn, qn);
    gemm_bt_kernel<<<dim3(64, 40), dim3(256), 0, stream>>>(qn, sn, out);
}

// Round 4
// 174.713 us; speedup vs baseline: 1.1457x; 1.0722x over previous
//
#include <hip/hip_runtime.h>
#include <stdint.h>

// Problem: cosine-similarity relations.
//   support: (2,5,1024,128) fp32 -> 10240 rows; query: (2,4,1024,128) -> 8192 rows
//   out: (2,4,5,1024,1024) fp32 = 167.8 MB
// MODEL RECALIBRATION (R8): the GEMM never shows in rocprof top-5 (all slots
// are ~103 us harness fillBuffer re-poisons of 671 MB) => gemm < 100 us and
// dur_us ~= fill(103) + norm(3) + gemm(~68 in R5). Optimize the 68 us vs the
// ~26 us write floor.
// R7 post-mortem: NT stores REGRESSED (+13 us) -- 64B-segment NT writes defeat
// L2 write-combining (partial-line RMW at HBM). Reverted to plain stores.
// R8 theory: per-block tile reads total 164 MB ~= write volume. Default
// mapping gives XCD k all tn==k blocks: every XCD re-reads all A-panels per y
// while 4 MB/y of streaming writes evict its L2 -> reads fall to HBM/L3 and
// the gemm is read+write-traffic bound (~330 MB -> ~51 us floor + overlap
// slop = 68 us). Fix (T1, bijective since 2560%8==0): tile t = bi*320 +
// j*64 + tm*8 + tn with bi=(b,i); bid -> xcd=bid&7=bi, pos=bid>>3. Each XCD
// owns one (b,i): read working set 2.25 MB < 4 MiB L2; instantaneous j-window
// hot set 512 KB. Tile reads become L2-hits.
// (R3 submission lost to GPUAcquisitionTimeout; identical resubmit.)

#define S_ROWS 10240
#define Q_ROWS 8192

typedef __attribute__((ext_vector_type(8))) short short8;   // 8 bf16 (4 VGPRs)
typedef __attribute__((ext_vector_type(4))) float floatx4;  // 16x16 MFMA acc
typedef __attribute__((ext_vector_type(4))) unsigned int uint4x;  // 16 B chunk

__device__ static inline unsigned short f32_to_bf16_rne(float f) {
    union { float f; uint32_t u; } c; c.f = f;
    uint32_t u = c.u;
    uint32_t r = u + 0x7FFFu + ((u >> 16) & 1u);   // round-to-nearest-even
    return (unsigned short)(r >> 16);
}

// ---------------- Kernel 1: L2-normalize rows of 128, cast to bf16 ----------
__global__ __launch_bounds__(256) void norm_cast_kernel(
    const float* __restrict__ support, const float* __restrict__ query,
    unsigned short* __restrict__ sn, unsigned short* __restrict__ qn)
{
    int wave = blockIdx.x * 4 + (threadIdx.x >> 6);
    int lane = threadIdx.x & 63;

    const float* src;
    unsigned short* dst;
    if (wave < S_ROWS) {
        src = support + (size_t)wave * 128;
        dst = sn + (size_t)wave * 128;
    } else {
        int r = wave - S_ROWS;
        src = query + (size_t)r * 128;
        dst = qn + (size_t)r * 128;
    }

    float2 v = ((const float2*)src)[lane];
    float s = v.x * v.x + v.y * v.y;
    #pragma unroll
    for (int off = 32; off > 0; off >>= 1) s += __shfl_xor(s, off, 64);
    float inv = 1.0f / fmaxf(sqrtf(s), 1e-12f);

    unsigned short lo = f32_to_bf16_rne(v.x * inv);
    unsigned short hi = f32_to_bf16_rne(v.y * inv);
    ((uint32_t*)dst)[lane] = ((uint32_t)hi << 16) | (uint32_t)lo;
}

// ---------------- Kernel 2: batched C = Qn * Sn^T via bf16 MFMA -------------
// 256 threads (4 waves), 128x128 tile, 64x64 per wave. A/B tiles staged in
// LDS (64 KB) with XOR-swizzled 16B units; conflict-free ds_read_b128.
// R8: XCD-chunked tile mapping -- each XCD owns one (b,i) slice.
__global__ __launch_bounds__(256) void gemm_bt_kernel(
    const unsigned short* __restrict__ qn, const unsigned short* __restrict__ sn,
    float* __restrict__ out)
{
    __shared__ unsigned short As[128 * 128];  // 32 KB, swizzled 16B units
    __shared__ unsigned short Bs[128 * 128];  // 32 KB, swizzled 16B units

    const int tid  = threadIdx.x;
    const int wave = tid >> 6;
    const int lane = tid & 63;

    // Tile decode: bid -> xcd-chunked (T1, bijective: 2560 % 8 == 0).
    const int bid = blockIdx.x;
    const int bi  = bid & 7;          // (b,i) = XCD id: per-XCD A set = 1 MB
    const int pos = bid >> 3;         // 0..319 within this XCD's chunk
    const int j   = pos >> 6;         // 0..4
    const int r6  = pos & 63;
    const int tm  = r6 >> 3;          // tn fastest -> A-panel reuse burst
    const int tn  = r6 & 7;
    const int b   = bi >> 2;

    const unsigned short* gA = qn + (((size_t)bi * 1024 + tm * 128) * 128);
    const unsigned short* gB = sn + (((size_t)(b * 5 + j) * 1024 + tn * 128) * 128);

    // Stage 2 x 32 KB. Tile = 2048 16B-units; thread t does units t+256*it.
    // Global loads fully coalesced; ds_write address swizzled.
    uint4x ra[8], rb[8];
    #pragma unroll
    for (int it = 0; it < 8; ++it) {
        ra[it] = ((const uint4x*)gA)[it * 256 + tid];
        rb[it] = ((const uint4x*)gB)[it * 256 + tid];
    }
    #pragma unroll
    for (int it = 0; it < 8; ++it) {
        const int u  = it * 256 + tid;
        const int r  = u >> 4;
        const int cl = u & 15;
        const int su = (r << 4) | (cl ^ (r & 15));   // swizzled LDS unit
        *(uint4x*)&As[su * 8] = ra[it];
        *(uint4x*)&Bs[su * 8] = rb[it];
    }

    const int wm   = (wave >> 1) * 64;
    const int wn   = (wave & 1) * 64;
    const int ml   = lane & 15;
    const int quad = lane >> 4;

    floatx4 acc[4][4] = {};

    __syncthreads();

    #pragma unroll
    for (int kb = 0; kb < 4; ++kb) {
        const int c = kb * 4 + quad;     // 16B-unit column (k-chunk) index
        short8 a[4], bf[4];
        #pragma unroll
        for (int mi = 0; mi < 4; ++mi) {
            const int arow = wm + mi * 16 + ml;          // arow & 15 == ml
            a[mi] = *(const short8*)&As[(((arow << 4) | (c ^ ml))) * 8];
        }
        #pragma unroll
        for (int ni = 0; ni < 4; ++ni) {
            const int brow = wn + ni * 16 + ml;
            bf[ni] = *(const short8*)&Bs[(((brow << 4) | (c ^ ml))) * 8];
        }
        #pragma unroll
        for (int mi = 0; mi < 4; ++mi)
            #pragma unroll
            for (int ni = 0; ni < 4; ++ni)
                acc[mi][ni] = __builtin_amdgcn_mfma_f32_16x16x32_bf16(
                    a[mi], bf[ni], acc[mi][ni], 0, 0, 0);
    }

    // Epilogue: C/D layout col=lane&15, row=quad*4+reg (m89/m91-verified).
    // Plain stores (NT regressed in R7: 64B-segment NT defeats write-combine).
    float* gC = out + ((size_t)(bi * 5 + j) << 20)
                    + (size_t)(tm * 128) * 1024 + tn * 128;
    #pragma unroll
    for (int mi = 0; mi < 4; ++mi) {
        #pragma unroll
        for (int r = 0; r < 4; ++r) {
            const int row = wm + mi * 16 + quad * 4 + r;
            float* rowp = gC + (size_t)row * 1024 + wn + ml;
            #pragma unroll
            for (int ni = 0; ni < 4; ++ni)
                rowp[ni * 16] = acc[mi][ni][r];
        }
    }
}

extern "C" void kernel_launch(void* const* d_in, const int* in_sizes, int n_in,
                              void* d_out, int out_size, void* d_ws, size_t ws_size,
                              hipStream_t stream) {
    const float* support = (const float*)d_in[0];   // (2,5,1024,128)
    const float* query   = (const float*)d_in[1];   // (2,4,1024,128)
    unsigned short* sn = (unsigned short*)d_ws;             // 10240*128 bf16
    unsigned short* qn = sn + (size_t)S_ROWS * 128;         //  8192*128 bf16
    float* out = (float*)d_out;

    norm_cast_kernel<<<dim3((S_ROWS + Q_ROWS) / 4), dim3(256), 0, stream>>>(
        support, query, sn, qn);
    gemm_bt_kernel<<<dim3(2560), dim3(256), 0, stream>>>(qn, sn, out);
}